// Round 1
// baseline (262.225 us; speedup 1.0000x reference)
//
#include <hip/hip_runtime.h>
#include <hip/hip_bf16.h>

#define T_TOKENS 2048
#define DMODEL   1024
#define NEXPERT  16
#define TOPK     2
#define NASSIGN  (T_TOKENS * TOPK)   // 4096

#define BM 128
#define BN 128
#define BK 32
#define LDSK 40   // padded LDS row stride in bf16 elems (80 B, 16B-aligned)

typedef __attribute__((ext_vector_type(8))) short  short8;
typedef __attribute__((ext_vector_type(4))) float  floatx4;
typedef __attribute__((ext_vector_type(8))) unsigned short ushort8;

__device__ __forceinline__ unsigned short f2bf(float f) {
    unsigned u = __builtin_bit_cast(unsigned, f);
    u += 0x7fff + ((u >> 16) & 1);   // RNE truncate to bf16
    return (unsigned short)(u >> 16);
}

// ---------------------------------------------------------------------------
// Routing: bucket assignments by expert. One block.
// ws layout (ints): counts[16] | offsets[16] | list[4096]
// ---------------------------------------------------------------------------
__global__ void build_routing(const int* __restrict__ gate_idx,
                              int* __restrict__ counts,
                              int* __restrict__ offsets,
                              int* __restrict__ list) {
    __shared__ int s_cnt[NEXPERT];
    __shared__ int s_off[NEXPERT];
    const int tid = threadIdx.x;
    if (tid < NEXPERT) s_cnt[tid] = 0;
    __syncthreads();
    for (int a = tid; a < NASSIGN; a += blockDim.x)
        atomicAdd(&s_cnt[gate_idx[a]], 1);
    __syncthreads();
    if (tid == 0) {
        int run = 0;
        for (int e = 0; e < NEXPERT; e++) { s_off[e] = run; run += s_cnt[e]; }
    }
    __syncthreads();
    if (tid < NEXPERT) {
        counts[tid]  = s_cnt[tid];
        offsets[tid] = s_off[tid];
        s_cnt[tid]   = s_off[tid];   // reuse as cursor
    }
    __syncthreads();
    for (int a = tid; a < NASSIGN; a += blockDim.x) {
        int e = gate_idx[a];
        int pos = atomicAdd(&s_cnt[e], 1);
        list[pos] = a;
    }
}

// ---------------------------------------------------------------------------
// Grouped GEMM: one block = (expert e, 128 gathered rows, 128 output cols).
// sA[m][k] : gathered x rows as bf16.  sB[n][k] : W[e] tile transposed (bf16).
// 4 waves, each computes 64x64 via 4x4 frags of mfma_f32_16x16x32_bf16.
// Epilogue: atomicAdd(score * (acc + bias)) into zeroed out.
// ---------------------------------------------------------------------------
__global__ __launch_bounds__(256) void moe_gemm(
    const float* __restrict__ x,       // [T, D]
    const float* __restrict__ W,       // [E, D, D]  (row = input dim k, col = out dim n)
    const float* __restrict__ bias,    // [E, D]
    const float* __restrict__ score,   // [T, TOPK] flat: score[a]
    const int*   __restrict__ counts,
    const int*   __restrict__ offsets,
    const int*   __restrict__ list,
    float*       __restrict__ out)     // [T, D]
{
    const int e   = blockIdx.z;
    const int cnt = counts[e];
    const int m0  = blockIdx.y * BM;
    if (m0 >= cnt) return;
    const int n0  = blockIdx.x * BN;
    const int off = offsets[e];

    __shared__ __align__(16) unsigned short sA[BM][LDSK];
    __shared__ __align__(16) unsigned short sB[BN][LDSK];

    const int tid = threadIdx.x;

    // ---- A staging map: thread -> (row, 16-float half)
    const int arow  = tid >> 1;
    const int ahalf = (tid & 1) * 16;
    const bool avalid = (m0 + arow) < cnt;
    int atok = 0;
    if (avalid) atok = list[off + m0 + arow] >> 1;
    const float* xsrc = x + atok * DMODEL + ahalf;

    // ---- B staging map: thread -> (k row, 16-col group); rotation kills bank conflicts
    const int bk  = tid >> 3;          // 0..31
    const int bng = tid & 7;           // n-group 0..7
    const int bn  = bng * 16;
    const float* wsrc = W + (e * DMODEL + bk) * DMODEL + n0 + bn;

    // ---- wave / fragment indices
    const int wave = tid >> 6;
    const int lane = tid & 63;
    const int wm   = (wave >> 1) * 64;
    const int wn   = (wave & 1) * 64;
    const int fr   = lane & 15;
    const int quad = lane >> 4;

    floatx4 acc[4][4] = {};

    for (int k0 = 0; k0 < DMODEL; k0 += BK) {
        // stage A (gathered x rows), f32 -> bf16, vectorized LDS writes
        {
            float4 v[4];
            if (avalid) {
                const float4* p = (const float4*)(xsrc + k0);
                v[0] = p[0]; v[1] = p[1]; v[2] = p[2]; v[3] = p[3];
            } else {
                v[0] = v[1] = v[2] = v[3] = make_float4(0.f, 0.f, 0.f, 0.f);
            }
            __align__(16) unsigned short cvt[16];
            #pragma unroll
            for (int i = 0; i < 4; i++) {
                cvt[4*i+0] = f2bf(v[i].x); cvt[4*i+1] = f2bf(v[i].y);
                cvt[4*i+2] = f2bf(v[i].z); cvt[4*i+3] = f2bf(v[i].w);
            }
            *(ushort8*)&sA[arow][ahalf]     = *(ushort8*)&cvt[0];
            *(ushort8*)&sA[arow][ahalf + 8] = *(ushort8*)&cvt[8];
        }
        // stage B: W[e][k0+bk][n0+bn .. +16) -> sB[n][k] (transpose via rotated scatter)
        {
            const float4* p = (const float4*)(wsrc + k0 * DMODEL);
            float4 v[4];
            v[0] = p[0]; v[1] = p[1]; v[2] = p[2]; v[3] = p[3];
            unsigned short cvt[16];
            #pragma unroll
            for (int i = 0; i < 4; i++) {
                cvt[4*i+0] = f2bf(v[i].x); cvt[4*i+1] = f2bf(v[i].y);
                cvt[4*i+2] = f2bf(v[i].z); cvt[4*i+3] = f2bf(v[i].w);
            }
            #pragma unroll
            for (int i = 0; i < 16; i++) {
                int m = (i + bng) & 15;    // rotate write order: 32-bank spread
                sB[bn + m][bk] = cvt[m];
            }
        }
        __syncthreads();

        short8 af[4], bfr[4];
        #pragma unroll
        for (int i = 0; i < 4; i++)
            af[i] = *(const short8*)&sA[wm + i * 16 + fr][quad * 8];
        #pragma unroll
        for (int i = 0; i < 4; i++)
            bfr[i] = *(const short8*)&sB[wn + i * 16 + fr][quad * 8];
        #pragma unroll
        for (int mi = 0; mi < 4; mi++)
            #pragma unroll
            for (int ni = 0; ni < 4; ni++)
                acc[mi][ni] = __builtin_amdgcn_mfma_f32_16x16x32_bf16(
                    af[mi], bfr[ni], acc[mi][ni], 0, 0, 0);
        __syncthreads();
    }

    // epilogue: C/D layout col = lane&15, row = quad*4 + r  [m89]
    const float* brow = bias + e * DMODEL;
    #pragma unroll
    for (int mi = 0; mi < 4; mi++) {
        const int rb = wm + mi * 16 + quad * 4;
        #pragma unroll
        for (int r = 0; r < 4; r++) {
            const int gm = m0 + rb + r;
            if (gm >= cnt) continue;
            const int a = list[off + gm];
            const int t = a >> 1;
            const float s = score[a];
            float* orow = out + t * DMODEL;
            #pragma unroll
            for (int ni = 0; ni < 4; ni++) {
                const int col = n0 + wn + ni * 16 + fr;
                atomicAdd(&orow[col], s * (acc[mi][ni][r] + brow[col]));
            }
        }
    }
}

extern "C" void kernel_launch(void* const* d_in, const int* in_sizes, int n_in,
                              void* d_out, int out_size, void* d_ws, size_t ws_size,
                              hipStream_t stream) {
    const float* x     = (const float*)d_in[0];   // [2048,1024] f32
    const int*   gidx  = (const int*)d_in[1];     // [2048,2] int
    const float* gsc   = (const float*)d_in[2];   // [2048,2] f32
    const float* W     = (const float*)d_in[3];   // [16,1024,1024] f32
    const float* bias  = (const float*)d_in[4];   // [16,1024] f32
    float* out = (float*)d_out;

    int* ws      = (int*)d_ws;
    int* counts  = ws;
    int* offsets = ws + 16;
    int* list    = ws + 32;

    hipMemsetAsync(d_out, 0, (size_t)T_TOKENS * DMODEL * sizeof(float), stream);
    build_routing<<<1, 256, 0, stream>>>(gidx, counts, offsets, list);

    dim3 grid(DMODEL / BN, (NASSIGN + BM - 1) / BM, NEXPERT);
    moe_gemm<<<grid, 256, 0, stream>>>(x, W, bias, gsc, counts, offsets, list, out);
}